// Round 4
// baseline (202.694 us; speedup 1.0000x reference)
//
#include <hip/hip_runtime.h>
#include <hip/hip_bf16.h>

typedef __hip_bfloat16 bf16;
typedef __attribute__((ext_vector_type(8))) short short8;   // bf16x8 MFMA frag (4 VGPR)
typedef __attribute__((ext_vector_type(4))) short short4v;  // bf16x4 (8 B)
typedef __attribute__((ext_vector_type(4))) float float4v;  // MFMA acc frag

// ---- geometry ----
#define HALO_H 18
#define HALO_W 10
#define CS 24          // xs channel stride: lane stride 48B = 12 dw -> 2-way banks, 16B aligned
#define KS 136         // hs k stride: row stride 272B -> 2-way banks, 16B aligned
#define XS_EL (HALO_W * HALO_H * CS)   // 4320

// ---- ws layout ----
// bf16:  W1E [128][160] (20480 el) + W2B [16][128] (2048 el)  = 45056 B
// float: b1e[128], b2[16] at byte 45056
// xT bf16 [b][h][w][c] at byte 65536, 16 MB
#define W2B_EL 20480
#define WSF_BYTE 45056
#define XT_BYTE 65536

__device__ __forceinline__ unsigned int bfbits(float f) {
    bf16 h = __float2bfloat16(f);
    unsigned short u;
    __builtin_memcpy(&u, &h, 2);
    return (unsigned int)u;
}

// One kernel: blocks [0, tb) transpose x -> xT bf16 [b][h][w][c];
// blocks [tb, tb+80) build fused weights.
__global__ void prep_all(const float* __restrict__ x,
                         const float* __restrict__ Wx, const float* __restrict__ bx,
                         const float* __restrict__ Wy, const float* __restrict__ by,
                         const float* __restrict__ W1, const float* __restrict__ b1,
                         const float* __restrict__ W2, const float* __restrict__ b2,
                         bf16* __restrict__ wsb, float* __restrict__ wsf,
                         bf16* __restrict__ xT, int tb) {
    int blk = blockIdx.x;
    int tid = threadIdx.x;
    if (blk < tb) {
        // ---- transpose one (b,h) row: x[b][c][h][0..127] -> xT[(b,h)][w][c] ----
        int b = blk >> 7;
        int w = tid >> 1, half = tid & 1;
        const float* src = x + (((size_t)(b * 16 + half * 8)) * 128 + (blk & 127)) * 128 + w;
        unsigned int pk[4];
#pragma unroll
        for (int i = 0; i < 4; ++i) {
            unsigned int lo = bfbits(src[(size_t)(2 * i) * 16384]);
            unsigned int hi = bfbits(src[(size_t)(2 * i + 1) * 16384]);
            pk[i] = lo | (hi << 16);
        }
        *(uint4*)(xT + ((size_t)blk * 128 + w) * 16 + half * 8) =
            make_uint4(pk[0], pk[1], pk[2], pk[3]);
        return;
    }
    // ---- fused weights ----
    int t = (blk - tb) * 256 + tid;
    int stride = 80 * 256;
    // W1_eff[j][k], k = g*16 + c, g = kh*3+kw (g==9 zero pad), K padded to 160
    for (int f = t; f < 128 * 160; f += stride) {
        int j = f / 160, k = f - j * 160;
        int g = k >> 4, c = k & 15;
        float v = 0.0f;
        if (g < 9) {
            for (int o = 0; o < 16; ++o) {
                float wx = Wx[(o * 16 + c) * 9 + g];
                float wy = Wy[(o * 16 + c) * 9 + g];
                v = fmaf(W1[j * 48 + o], wx, v);
                v = fmaf(W1[j * 48 + 16 + o], wy, v);
            }
            if (g == 4) v += W1[j * 48 + 32 + c];  // identity (concat-x) center tap
        }
        wsb[f] = __float2bfloat16(v);
    }
    for (int f = t; f < 2048; f += stride) wsb[W2B_EL + f] = __float2bfloat16(W2[f]);
    for (int j = t; j < 128; j += stride) {
        float v = b1[j];
        for (int o = 0; o < 16; ++o) {
            v = fmaf(W1[j * 48 + o], bx[o], v);
            v = fmaf(W1[j * 48 + 16 + o], by[o], v);
        }
        wsf[j] = v;
    }
    if (t < 16) wsf[128 + t] = b2[t];
}

// ---------------- main kernel (transposed-x path, pipelined) ----------------
__global__ __launch_bounds__(256, 3) void nca_mfma_t(const bf16* __restrict__ xT,
                                                     const bf16* __restrict__ wsb,
                                                     const float* __restrict__ wsf,
                                                     float* __restrict__ out,
                                                     int gridTiles) {
    __shared__ __align__(16) bf16 xs[2][XS_EL];
    __shared__ __align__(16) bf16 hs[128 * KS];

    const int tid = threadIdx.x;
    const int wave = tid >> 6;
    const int lane = tid & 63;
    const int hl = lane & 15;
    const int quad = lane >> 4;
    const int r0 = quad * 4;
    const int mgrp = wave >> 1;
    const int ngrp = wave & 1;

    // ---- one-time: A fragments (W1e), W2 frags, biases ----
    short8 afrag[4][5];
#pragma unroll
    for (int mt = 0; mt < 4; ++mt) {
        int m = mgrp * 64 + mt * 16 + hl;
#pragma unroll
        for (int q = 0; q < 5; ++q)
            afrag[mt][q] = *(const short8*)(wsb + m * 160 + q * 32 + quad * 8);
    }
    short8 w2frag[4];
#pragma unroll
    for (int r = 0; r < 4; ++r)
        w2frag[r] = *(const short8*)(wsb + W2B_EL + hl * 128 + r * 32 + quad * 8);
    float b1r[4][4];
#pragma unroll
    for (int mt = 0; mt < 4; ++mt)
#pragma unroll
        for (int r = 0; r < 4; ++r) b1r[mt][r] = wsf[mgrp * 64 + mt * 16 + r0 + r];
    float b2r[4];
#pragma unroll
    for (int r = 0; r < 4; ++r) b2r[r] = wsf[128 + r0 + r];

    // ---- staging decode (constant per thread): 360 dwordx4 ops per tile ----
    const int hh0 = tid / 20, rr0 = tid % 20;
    const int sww0 = rr0 >> 1, shf0 = rr0 & 1;
    const int f1 = tid + 256;
    const int hh1 = f1 / 20, rr1 = f1 % 20;
    const int sww1 = rr1 >> 1, shf1 = rr1 & 1;
    const bool has1 = (tid < 104);

    uint4 pre0, pre1;

#define LOAD_TILE(T)                                                                  \
    {                                                                                 \
        int b_ = (T) >> 7, rem_ = (T) & 127;                                          \
        int w0_ = (rem_ >> 3) * 8, h0_ = (rem_ & 7) * 16;                             \
        {                                                                             \
            int gh = h0_ - 1 + hh0, gw = w0_ - 1 + sww0;                              \
            bool ok = ((unsigned)gh < 128u) && ((unsigned)gw < 128u);                 \
            long off = (((long)b_ << 14) + gh * 128 + gw) * 16 + (shf0 << 3);         \
            const uint4* p = (const uint4*)(xT + (ok ? off : 0));                     \
            uint4 v = *p;                                                             \
            if (!ok) { v.x = 0; v.y = 0; v.z = 0; v.w = 0; }                          \
            pre0 = v;                                                                 \
        }                                                                             \
        if (has1) {                                                                   \
            int gh = h0_ - 1 + hh1, gw = w0_ - 1 + sww1;                              \
            bool ok = ((unsigned)gh < 128u) && ((unsigned)gw < 128u);                 \
            long off = (((long)b_ << 14) + gh * 128 + gw) * 16 + (shf1 << 3);         \
            const uint4* p = (const uint4*)(xT + (ok ? off : 0));                     \
            uint4 v = *p;                                                             \
            if (!ok) { v.x = 0; v.y = 0; v.z = 0; v.w = 0; }                          \
            pre1 = v;                                                                 \
        }                                                                             \
    }

    int t = blockIdx.x;
    LOAD_TILE(t);
    int buf = 0;

    for (; t < 4096; t += gridTiles) {
        const int b = t >> 7;
        const int rem = t & 127;
        const int w0 = (rem >> 3) * 8;
        const int h0 = (rem & 7) * 16;

        // ---- commit prefetched tile -> xs[buf] ----
        *(uint4*)(&xs[buf][(sww0 * HALO_H + hh0) * CS + shf0 * 8]) = pre0;
        if (has1) *(uint4*)(&xs[buf][(sww1 * HALO_H + hh1) * CS + shf1 * 8]) = pre1;
        __syncthreads();  // xs[buf] ready; prev iter's hs reads all done

        // ---- prefetch next tile's x into registers (flies during GEMM1) ----
        int tn = t + gridTiles;
        if (tn < 4096) LOAD_TILE(tn);

        // ---- GEMM1: acc = W1e @ patches ----
        float4v acc[4][4];
#pragma unroll
        for (int mt = 0; mt < 4; ++mt)
#pragma unroll
            for (int nt = 0; nt < 4; ++nt) acc[mt][nt] = (float4v)0.0f;

#pragma unroll
        for (int q = 0; q < 5; ++q) {
            int g = q * 2 + (quad >> 1);
            if (g > 8) g = 8;  // K-pad: A rows are zero there
            int kh = g / 3, kw = g - kh * 3;
            int c0 = (quad & 1) * 8;
            short8 bfrag[4];
#pragma unroll
            for (int nt = 0; nt < 4; ++nt) {
                int ww = ngrp * 4 + nt + kw;
                bfrag[nt] = *(const short8*)(&xs[buf][(ww * HALO_H + hl + kh) * CS + c0]);
            }
#pragma unroll
            for (int nt = 0; nt < 4; ++nt)
#pragma unroll
                for (int mt = 0; mt < 4; ++mt)
                    acc[mt][nt] = __builtin_amdgcn_mfma_f32_16x16x32_bf16(
                        afrag[mt][q], bfrag[nt], acc[mt][nt], 0, 0, 0);
        }

        // ---- epilogue 1: bias + relu -> hs[pixel][m] bf16 ----
#pragma unroll
        for (int mt = 0; mt < 4; ++mt)
#pragma unroll
            for (int nt = 0; nt < 4; ++nt) {
                int p = (ngrp * 4 + nt) * 16 + hl;
                int m = mgrp * 64 + mt * 16 + r0;
                short4v pk;
#pragma unroll
                for (int r = 0; r < 4; ++r) {
                    float v = acc[mt][nt][r] + b1r[mt][r];
                    v = fmaxf(v, 0.0f);
                    bf16 hb = __float2bfloat16(v);
                    pk[r] = *reinterpret_cast<short*>(&hb);
                }
                *(short4v*)(hs + p * KS + m) = pk;
            }
        __syncthreads();  // hs ready; xs[buf] reads done

        // ---- GEMM2: out16 = W2 @ h ----
        float4v acc2[2];
        acc2[0] = (float4v)0.0f;
        acc2[1] = (float4v)0.0f;
#pragma unroll
        for (int r = 0; r < 4; ++r) {
#pragma unroll
            for (int i = 0; i < 2; ++i) {
                int p = (wave * 2 + i) * 16 + hl;
                short8 bfrag = *(const short8*)(hs + p * KS + r * 32 + quad * 8);
                acc2[i] = __builtin_amdgcn_mfma_f32_16x16x32_bf16(
                    w2frag[r], bfrag, acc2[i], 0, 0, 0);
            }
        }

        // ---- store out[b][w0+nt][h0+hl][r0..r0+3] fp32, coalesced ----
#pragma unroll
        for (int i = 0; i < 2; ++i) {
            int nt = wave * 2 + i;
            size_t ofs = (((size_t)b * 128 + (w0 + nt)) * 128 + (h0 + hl)) * 16 + r0;
            float4 v = make_float4(acc2[i][0] + b2r[0], acc2[i][1] + b2r[1],
                                   acc2[i][2] + b2r[2], acc2[i][3] + b2r[3]);
            *(float4*)(out + ofs) = v;
        }
        buf ^= 1;
    }
#undef LOAD_TILE
}

// ---------------- fallback (round-3 proven kernel, fp32 x) ----------------
__global__ __launch_bounds__(256, 2) void nca_mfma_fb(const float* __restrict__ x,
                                                      const bf16* __restrict__ wsb,
                                                      const float* __restrict__ wsf,
                                                      float* __restrict__ out,
                                                      int gridTiles) {
    __shared__ bf16 xs[HALO_W * HALO_H * CS];
    __shared__ bf16 hs[128 * KS];

    const int tid = threadIdx.x;
    const int wave = tid >> 6;
    const int lane = tid & 63;
    const int hl = lane & 15;
    const int quad = lane >> 4;
    const int r0 = quad * 4;
    const int mgrp = wave >> 1;
    const int ngrp = wave & 1;

    short8 afrag[4][5];
#pragma unroll
    for (int mt = 0; mt < 4; ++mt) {
        int m = mgrp * 64 + mt * 16 + hl;
#pragma unroll
        for (int q = 0; q < 5; ++q)
            afrag[mt][q] = *(const short8*)(wsb + m * 160 + q * 32 + quad * 8);
    }
    short8 w2frag[4];
#pragma unroll
    for (int r = 0; r < 4; ++r)
        w2frag[r] = *(const short8*)(wsb + W2B_EL + hl * 128 + r * 32 + quad * 8);
    float b1r[4][4];
#pragma unroll
    for (int mt = 0; mt < 4; ++mt)
#pragma unroll
        for (int r = 0; r < 4; ++r) b1r[mt][r] = wsf[mgrp * 64 + mt * 16 + r0 + r];
    float b2r[4];
#pragma unroll
    for (int r = 0; r < 4; ++r) b2r[r] = wsf[128 + r0 + r];

    for (int t = blockIdx.x; t < 4096; t += gridTiles) {
        int b = t >> 7;
        int rem = t & 127;
        int wt = rem >> 3, ht = rem & 7;
        int h0 = ht * 16, w0 = wt * 8;

        __syncthreads();

        const float* xb = x + (size_t)b * 16 * 128 * 128;
        for (int f = tid; f < 16 * HALO_H * HALO_W; f += 256) {
            int c = f / (HALO_H * HALO_W);
            int rr = f - c * (HALO_H * HALO_W);
            int hh = rr / HALO_W;
            int ww = rr - hh * HALO_W;
            int gh = h0 - 1 + hh, gw = w0 - 1 + ww;
            float v = 0.0f;
            if ((unsigned)gh < 128u && (unsigned)gw < 128u)
                v = xb[(c * 128 + gh) * 128 + gw];
            xs[(ww * HALO_H + hh) * CS + c] = __float2bfloat16(v);
        }
        __syncthreads();

        float4v acc[4][4];
#pragma unroll
        for (int mt = 0; mt < 4; ++mt)
#pragma unroll
            for (int nt = 0; nt < 4; ++nt) acc[mt][nt] = (float4v)0.0f;

#pragma unroll
        for (int q = 0; q < 5; ++q) {
            int g = q * 2 + (quad >> 1);
            if (g > 8) g = 8;
            int kh = g / 3, kw = g - kh * 3;
            int c0 = (quad & 1) * 8;
            short8 bfrag[4];
#pragma unroll
            for (int nt = 0; nt < 4; ++nt) {
                int ww = ngrp * 4 + nt + kw;
                bfrag[nt] = *(const short8*)(xs + (ww * HALO_H + hl + kh) * CS + c0);
            }
#pragma unroll
            for (int nt = 0; nt < 4; ++nt)
#pragma unroll
                for (int mt = 0; mt < 4; ++mt)
                    acc[mt][nt] = __builtin_amdgcn_mfma_f32_16x16x32_bf16(
                        afrag[mt][q], bfrag[nt], acc[mt][nt], 0, 0, 0);
        }

#pragma unroll
        for (int mt = 0; mt < 4; ++mt)
#pragma unroll
            for (int nt = 0; nt < 4; ++nt) {
                int p = (ngrp * 4 + nt) * 16 + hl;
                int m = mgrp * 64 + mt * 16 + r0;
                short4v pk;
#pragma unroll
                for (int r = 0; r < 4; ++r) {
                    float v = acc[mt][nt][r] + b1r[mt][r];
                    v = fmaxf(v, 0.0f);
                    bf16 hb = __float2bfloat16(v);
                    pk[r] = *reinterpret_cast<short*>(&hb);
                }
                *(short4v*)(hs + p * KS + m) = pk;
            }
        __syncthreads();

        float4v acc2[2];
        acc2[0] = (float4v)0.0f;
        acc2[1] = (float4v)0.0f;
#pragma unroll
        for (int r = 0; r < 4; ++r) {
#pragma unroll
            for (int i = 0; i < 2; ++i) {
                int p = (wave * 2 + i) * 16 + hl;
                short8 bfrag = *(const short8*)(hs + p * KS + r * 32 + quad * 8);
                acc2[i] = __builtin_amdgcn_mfma_f32_16x16x32_bf16(
                    w2frag[r], bfrag, acc2[i], 0, 0, 0);
            }
        }

#pragma unroll
        for (int i = 0; i < 2; ++i) {
            int nt = wave * 2 + i;
            size_t ofs = (((size_t)b * 128 + (w0 + nt)) * 128 + (h0 + hl)) * 16 + r0;
            float4 v = make_float4(acc2[i][0] + b2r[0], acc2[i][1] + b2r[1],
                                   acc2[i][2] + b2r[2], acc2[i][3] + b2r[3]);
            *(float4*)(out + ofs) = v;
        }
    }
}

extern "C" void kernel_launch(void* const* d_in, const int* in_sizes, int n_in,
                              void* d_out, int out_size, void* d_ws, size_t ws_size,
                              hipStream_t stream) {
    const float* x  = (const float*)d_in[0];
    const float* Wx = (const float*)d_in[1];
    const float* bx = (const float*)d_in[2];
    const float* Wy = (const float*)d_in[3];
    const float* by = (const float*)d_in[4];
    const float* W1 = (const float*)d_in[5];
    const float* b1 = (const float*)d_in[6];
    const float* W2 = (const float*)d_in[7];
    const float* b2 = (const float*)d_in[8];
    bf16* wsb = (bf16*)d_ws;
    float* wsf = (float*)((char*)d_ws + WSF_BYTE);
    bf16* xT = (bf16*)((char*)d_ws + XT_BYTE);
    float* out = (float*)d_out;

    const size_t need = (size_t)XT_BYTE + (size_t)32 * 128 * 128 * 16 * 2;  // 16.8 MB
    const bool big = ws_size >= need;
    const int tb = big ? 4096 : 0;

    hipLaunchKernelGGL(prep_all, dim3(tb + 80), dim3(256), 0, stream,
                       x, Wx, bx, Wy, by, W1, b1, W2, b2, wsb, wsf, xT, tb);
    if (big) {
        const int grid = 1536;  // 3 blocks/CU resident, ~2.7 tiles/block
        hipLaunchKernelGGL(nca_mfma_t, dim3(grid), dim3(256), 0, stream,
                           xT, wsb, wsf, out, grid);
    } else {
        const int grid = 1024;
        hipLaunchKernelGGL(nca_mfma_fb, dim3(grid), dim3(256), 0, stream,
                           x, wsb, wsf, out, grid);
    }
}

// Round 5
// 124.122 us; speedup vs baseline: 1.6330x; 1.6330x over previous
//
#include <hip/hip_runtime.h>
#include <hip/hip_bf16.h>

typedef __hip_bfloat16 bf16;
typedef __attribute__((ext_vector_type(8))) short short8;   // bf16x8 MFMA frag (4 VGPR)
typedef __attribute__((ext_vector_type(4))) short short4v;  // bf16x4 (8 B)
typedef __attribute__((ext_vector_type(4))) float float4v;  // MFMA acc frag

// ---- geometry ----
#define HALO_H 18
#define HALO_W 10
#define CS 24          // xs channel stride: lane stride 48B = 12 dw -> 2-way banks, 16B aligned
#define KS 136         // hs k stride: row stride 272B -> 2-way banks, 16B aligned
#define XS_EL (HALO_W * HALO_H * CS)   // 4320

// ---- ws layout ----
// bf16:  W1E [128][160] (20480 el) + W2B [16][128] (2048 el)  = 45056 B
// float: b1e[128], b2[16] at byte 45056
// xT bf16 [b][h][w][c] at byte 65536, 16 MB
#define W2B_EL 20480
#define WSF_BYTE 45056
#define XT_BYTE 65536

__device__ __forceinline__ unsigned int bfbits(float f) {
    bf16 h = __float2bfloat16(f);
    unsigned short u;
    __builtin_memcpy(&u, &h, 2);
    return (unsigned int)u;
}

// One kernel: blocks [0, tb) transpose x -> xT bf16 [b][h][w][c];
// blocks [tb, tb+80) build fused weights.
__global__ void prep_all(const float* __restrict__ x,
                         const float* __restrict__ Wx, const float* __restrict__ bx,
                         const float* __restrict__ Wy, const float* __restrict__ by,
                         const float* __restrict__ W1, const float* __restrict__ b1,
                         const float* __restrict__ W2, const float* __restrict__ b2,
                         bf16* __restrict__ wsb, float* __restrict__ wsf,
                         bf16* __restrict__ xT, int tb) {
    int blk = blockIdx.x;
    int tid = threadIdx.x;
    if (blk < tb) {
        // ---- transpose one (b,h) row: x[b][c][h][0..127] -> xT[(b,h)][w][c] ----
        int b = blk >> 7;
        int w = tid >> 1, half = tid & 1;
        const float* src = x + (((size_t)(b * 16 + half * 8)) * 128 + (blk & 127)) * 128 + w;
        unsigned int pk[4];
#pragma unroll
        for (int i = 0; i < 4; ++i) {
            unsigned int lo = bfbits(src[(size_t)(2 * i) * 16384]);
            unsigned int hi = bfbits(src[(size_t)(2 * i + 1) * 16384]);
            pk[i] = lo | (hi << 16);
        }
        *(uint4*)(xT + ((size_t)blk * 128 + w) * 16 + half * 8) =
            make_uint4(pk[0], pk[1], pk[2], pk[3]);
        return;
    }
    // ---- fused weights ----
    int t = (blk - tb) * 256 + tid;
    int stride = 80 * 256;
    // W1_eff[j][k], k = g*16 + c, g = kh*3+kw (g==9 zero pad), K padded to 160
    for (int f = t; f < 128 * 160; f += stride) {
        int j = f / 160, k = f - j * 160;
        int g = k >> 4, c = k & 15;
        float v = 0.0f;
        if (g < 9) {
            for (int o = 0; o < 16; ++o) {
                float wx = Wx[(o * 16 + c) * 9 + g];
                float wy = Wy[(o * 16 + c) * 9 + g];
                v = fmaf(W1[j * 48 + o], wx, v);
                v = fmaf(W1[j * 48 + 16 + o], wy, v);
            }
            if (g == 4) v += W1[j * 48 + 32 + c];  // identity (concat-x) center tap
        }
        wsb[f] = __float2bfloat16(v);
    }
    for (int f = t; f < 2048; f += stride) wsb[W2B_EL + f] = __float2bfloat16(W2[f]);
    for (int j = t; j < 128; j += stride) {
        float v = b1[j];
        for (int o = 0; o < 16; ++o) {
            v = fmaf(W1[j * 48 + o], bx[o], v);
            v = fmaf(W1[j * 48 + 16 + o], by[o], v);
        }
        wsf[j] = v;
    }
    if (t < 16) wsf[128 + t] = b2[t];
}

// ---------------- main kernel (transposed-x path, pipelined) ----------------
// __launch_bounds__(256,2): 256-VGPR budget. (256,3) forced spills in round 4
// (VGPR 84 + 150 MB scratch traffic) — register set needs ~190 VGPRs.
__global__ __launch_bounds__(256, 2) void nca_mfma_t(const bf16* __restrict__ xT,
                                                     const bf16* __restrict__ wsb,
                                                     const float* __restrict__ wsf,
                                                     float* __restrict__ out,
                                                     int gridTiles) {
    __shared__ __align__(16) bf16 xs[2][XS_EL];
    __shared__ __align__(16) bf16 hs[128 * KS];

    const int tid = threadIdx.x;
    const int wave = tid >> 6;
    const int lane = tid & 63;
    const int hl = lane & 15;
    const int quad = lane >> 4;
    const int r0 = quad * 4;
    const int mgrp = wave >> 1;
    const int ngrp = wave & 1;

    // ---- one-time: A fragments (W1e), W2 frags, biases ----
    short8 afrag[4][5];
#pragma unroll
    for (int mt = 0; mt < 4; ++mt) {
        int m = mgrp * 64 + mt * 16 + hl;
#pragma unroll
        for (int q = 0; q < 5; ++q)
            afrag[mt][q] = *(const short8*)(wsb + m * 160 + q * 32 + quad * 8);
    }
    short8 w2frag[4];
#pragma unroll
    for (int r = 0; r < 4; ++r)
        w2frag[r] = *(const short8*)(wsb + W2B_EL + hl * 128 + r * 32 + quad * 8);
    float b1r[4][4];
#pragma unroll
    for (int mt = 0; mt < 4; ++mt)
#pragma unroll
        for (int r = 0; r < 4; ++r) b1r[mt][r] = wsf[mgrp * 64 + mt * 16 + r0 + r];
    float b2r[4];
#pragma unroll
    for (int r = 0; r < 4; ++r) b2r[r] = wsf[128 + r0 + r];

    // ---- staging decode (constant per thread): 360 dwordx4 ops per tile ----
    const int hh0 = tid / 20, rr0 = tid % 20;
    const int sww0 = rr0 >> 1, shf0 = rr0 & 1;
    const int f1 = tid + 256;
    const int hh1 = f1 / 20, rr1 = f1 % 20;
    const int sww1 = rr1 >> 1, shf1 = rr1 & 1;
    const bool has1 = (tid < 104);

    uint4 pre0, pre1;

#define LOAD_TILE(T)                                                                  \
    {                                                                                 \
        int b_ = (T) >> 7, rem_ = (T) & 127;                                          \
        int w0_ = (rem_ >> 3) * 8, h0_ = (rem_ & 7) * 16;                             \
        {                                                                             \
            int gh = h0_ - 1 + hh0, gw = w0_ - 1 + sww0;                              \
            bool ok = ((unsigned)gh < 128u) && ((unsigned)gw < 128u);                 \
            long off = (((long)b_ << 14) + gh * 128 + gw) * 16 + (shf0 << 3);         \
            const uint4* p = (const uint4*)(xT + (ok ? off : 0));                     \
            uint4 v = *p;                                                             \
            if (!ok) { v.x = 0; v.y = 0; v.z = 0; v.w = 0; }                          \
            pre0 = v;                                                                 \
        }                                                                             \
        if (has1) {                                                                   \
            int gh = h0_ - 1 + hh1, gw = w0_ - 1 + sww1;                              \
            bool ok = ((unsigned)gh < 128u) && ((unsigned)gw < 128u);                 \
            long off = (((long)b_ << 14) + gh * 128 + gw) * 16 + (shf1 << 3);         \
            const uint4* p = (const uint4*)(xT + (ok ? off : 0));                     \
            uint4 v = *p;                                                             \
            if (!ok) { v.x = 0; v.y = 0; v.z = 0; v.w = 0; }                          \
            pre1 = v;                                                                 \
        }                                                                             \
    }

    int t = blockIdx.x;
    LOAD_TILE(t);
    int buf = 0;

    for (; t < 4096; t += gridTiles) {
        const int b = t >> 7;
        const int rem = t & 127;
        const int w0 = (rem >> 3) * 8;
        const int h0 = (rem & 7) * 16;

        // ---- commit prefetched tile -> xs[buf] ----
        *(uint4*)(&xs[buf][(sww0 * HALO_H + hh0) * CS + shf0 * 8]) = pre0;
        if (has1) *(uint4*)(&xs[buf][(sww1 * HALO_H + hh1) * CS + shf1 * 8]) = pre1;
        __syncthreads();  // xs[buf] ready; prev iter's hs reads all done

        // ---- prefetch next tile's x into registers (flies during GEMM1) ----
        int tn = t + gridTiles;
        if (tn < 4096) LOAD_TILE(tn);

        // ---- GEMM1: acc = W1e @ patches ----
        float4v acc[4][4];
#pragma unroll
        for (int mt = 0; mt < 4; ++mt)
#pragma unroll
            for (int nt = 0; nt < 4; ++nt) acc[mt][nt] = (float4v)0.0f;

#pragma unroll
        for (int q = 0; q < 5; ++q) {
            int g = q * 2 + (quad >> 1);
            if (g > 8) g = 8;  // K-pad: A rows are zero there
            int kh = g / 3, kw = g - kh * 3;
            int c0 = (quad & 1) * 8;
            short8 bfrag[4];
#pragma unroll
            for (int nt = 0; nt < 4; ++nt) {
                int ww = ngrp * 4 + nt + kw;
                bfrag[nt] = *(const short8*)(&xs[buf][(ww * HALO_H + hl + kh) * CS + c0]);
            }
#pragma unroll
            for (int nt = 0; nt < 4; ++nt)
#pragma unroll
                for (int mt = 0; mt < 4; ++mt)
                    acc[mt][nt] = __builtin_amdgcn_mfma_f32_16x16x32_bf16(
                        afrag[mt][q], bfrag[nt], acc[mt][nt], 0, 0, 0);
        }

        // ---- epilogue 1: bias + relu -> hs[pixel][m] bf16 ----
#pragma unroll
        for (int mt = 0; mt < 4; ++mt)
#pragma unroll
            for (int nt = 0; nt < 4; ++nt) {
                int p = (ngrp * 4 + nt) * 16 + hl;
                int m = mgrp * 64 + mt * 16 + r0;
                short4v pk;
#pragma unroll
                for (int r = 0; r < 4; ++r) {
                    float v = acc[mt][nt][r] + b1r[mt][r];
                    v = fmaxf(v, 0.0f);
                    bf16 hb = __float2bfloat16(v);
                    pk[r] = *reinterpret_cast<short*>(&hb);
                }
                *(short4v*)(hs + p * KS + m) = pk;
            }
        __syncthreads();  // hs ready; xs[buf] reads done

        // ---- GEMM2: out16 = W2 @ h ----
        float4v acc2[2];
        acc2[0] = (float4v)0.0f;
        acc2[1] = (float4v)0.0f;
#pragma unroll
        for (int r = 0; r < 4; ++r) {
#pragma unroll
            for (int i = 0; i < 2; ++i) {
                int p = (wave * 2 + i) * 16 + hl;
                short8 bfrag = *(const short8*)(hs + p * KS + r * 32 + quad * 8);
                acc2[i] = __builtin_amdgcn_mfma_f32_16x16x32_bf16(
                    w2frag[r], bfrag, acc2[i], 0, 0, 0);
            }
        }

        // ---- store out[b][w0+nt][h0+hl][r0..r0+3] fp32, coalesced ----
#pragma unroll
        for (int i = 0; i < 2; ++i) {
            int nt = wave * 2 + i;
            size_t ofs = (((size_t)b * 128 + (w0 + nt)) * 128 + (h0 + hl)) * 16 + r0;
            float4 v = make_float4(acc2[i][0] + b2r[0], acc2[i][1] + b2r[1],
                                   acc2[i][2] + b2r[2], acc2[i][3] + b2r[3]);
            *(float4*)(out + ofs) = v;
        }
        buf ^= 1;
    }
#undef LOAD_TILE
}

// ---------------- fallback (round-3 proven kernel, fp32 x) ----------------
__global__ __launch_bounds__(256, 2) void nca_mfma_fb(const float* __restrict__ x,
                                                      const bf16* __restrict__ wsb,
                                                      const float* __restrict__ wsf,
                                                      float* __restrict__ out,
                                                      int gridTiles) {
    __shared__ bf16 xs[HALO_W * HALO_H * CS];
    __shared__ bf16 hs[128 * KS];

    const int tid = threadIdx.x;
    const int wave = tid >> 6;
    const int lane = tid & 63;
    const int hl = lane & 15;
    const int quad = lane >> 4;
    const int r0 = quad * 4;
    const int mgrp = wave >> 1;
    const int ngrp = wave & 1;

    short8 afrag[4][5];
#pragma unroll
    for (int mt = 0; mt < 4; ++mt) {
        int m = mgrp * 64 + mt * 16 + hl;
#pragma unroll
        for (int q = 0; q < 5; ++q)
            afrag[mt][q] = *(const short8*)(wsb + m * 160 + q * 32 + quad * 8);
    }
    short8 w2frag[4];
#pragma unroll
    for (int r = 0; r < 4; ++r)
        w2frag[r] = *(const short8*)(wsb + W2B_EL + hl * 128 + r * 32 + quad * 8);
    float b1r[4][4];
#pragma unroll
    for (int mt = 0; mt < 4; ++mt)
#pragma unroll
        for (int r = 0; r < 4; ++r) b1r[mt][r] = wsf[mgrp * 64 + mt * 16 + r0 + r];
    float b2r[4];
#pragma unroll
    for (int r = 0; r < 4; ++r) b2r[r] = wsf[128 + r0 + r];

    for (int t = blockIdx.x; t < 4096; t += gridTiles) {
        int b = t >> 7;
        int rem = t & 127;
        int wt = rem >> 3, ht = rem & 7;
        int h0 = ht * 16, w0 = wt * 8;

        __syncthreads();

        const float* xb = x + (size_t)b * 16 * 128 * 128;
        for (int f = tid; f < 16 * HALO_H * HALO_W; f += 256) {
            int c = f / (HALO_H * HALO_W);
            int rr = f - c * (HALO_H * HALO_W);
            int hh = rr / HALO_W;
            int ww = rr - hh * HALO_W;
            int gh = h0 - 1 + hh, gw = w0 - 1 + ww;
            float v = 0.0f;
            if ((unsigned)gh < 128u && (unsigned)gw < 128u)
                v = xb[(c * 128 + gh) * 128 + gw];
            xs[(ww * HALO_H + hh) * CS + c] = __float2bfloat16(v);
        }
        __syncthreads();

        float4v acc[4][4];
#pragma unroll
        for (int mt = 0; mt < 4; ++mt)
#pragma unroll
            for (int nt = 0; nt < 4; ++nt) acc[mt][nt] = (float4v)0.0f;

#pragma unroll
        for (int q = 0; q < 5; ++q) {
            int g = q * 2 + (quad >> 1);
            if (g > 8) g = 8;
            int kh = g / 3, kw = g - kh * 3;
            int c0 = (quad & 1) * 8;
            short8 bfrag[4];
#pragma unroll
            for (int nt = 0; nt < 4; ++nt) {
                int ww = ngrp * 4 + nt + kw;
                bfrag[nt] = *(const short8*)(xs + (ww * HALO_H + hl + kh) * CS + c0);
            }
#pragma unroll
            for (int nt = 0; nt < 4; ++nt)
#pragma unroll
                for (int mt = 0; mt < 4; ++mt)
                    acc[mt][nt] = __builtin_amdgcn_mfma_f32_16x16x32_bf16(
                        afrag[mt][q], bfrag[nt], acc[mt][nt], 0, 0, 0);
        }

#pragma unroll
        for (int mt = 0; mt < 4; ++mt)
#pragma unroll
            for (int nt = 0; nt < 4; ++nt) {
                int p = (ngrp * 4 + nt) * 16 + hl;
                int m = mgrp * 64 + mt * 16 + r0;
                short4v pk;
#pragma unroll
                for (int r = 0; r < 4; ++r) {
                    float v = acc[mt][nt][r] + b1r[mt][r];
                    v = fmaxf(v, 0.0f);
                    bf16 hb = __float2bfloat16(v);
                    pk[r] = *reinterpret_cast<short*>(&hb);
                }
                *(short4v*)(hs + p * KS + m) = pk;
            }
        __syncthreads();

        float4v acc2[2];
        acc2[0] = (float4v)0.0f;
        acc2[1] = (float4v)0.0f;
#pragma unroll
        for (int r = 0; r < 4; ++r) {
#pragma unroll
            for (int i = 0; i < 2; ++i) {
                int p = (wave * 2 + i) * 16 + hl;
                short8 bfrag = *(const short8*)(hs + p * KS + r * 32 + quad * 8);
                acc2[i] = __builtin_amdgcn_mfma_f32_16x16x32_bf16(
                    w2frag[r], bfrag, acc2[i], 0, 0, 0);
            }
        }

#pragma unroll
        for (int i = 0; i < 2; ++i) {
            int nt = wave * 2 + i;
            size_t ofs = (((size_t)b * 128 + (w0 + nt)) * 128 + (h0 + hl)) * 16 + r0;
            float4 v = make_float4(acc2[i][0] + b2r[0], acc2[i][1] + b2r[1],
                                   acc2[i][2] + b2r[2], acc2[i][3] + b2r[3]);
            *(float4*)(out + ofs) = v;
        }
    }
}

extern "C" void kernel_launch(void* const* d_in, const int* in_sizes, int n_in,
                              void* d_out, int out_size, void* d_ws, size_t ws_size,
                              hipStream_t stream) {
    const float* x  = (const float*)d_in[0];
    const float* Wx = (const float*)d_in[1];
    const float* bx = (const float*)d_in[2];
    const float* Wy = (const float*)d_in[3];
    const float* by = (const float*)d_in[4];
    const float* W1 = (const float*)d_in[5];
    const float* b1 = (const float*)d_in[6];
    const float* W2 = (const float*)d_in[7];
    const float* b2 = (const float*)d_in[8];
    bf16* wsb = (bf16*)d_ws;
    float* wsf = (float*)((char*)d_ws + WSF_BYTE);
    bf16* xT = (bf16*)((char*)d_ws + XT_BYTE);
    float* out = (float*)d_out;

    const size_t need = (size_t)XT_BYTE + (size_t)32 * 128 * 128 * 16 * 2;  // 16.8 MB
    const bool big = ws_size >= need;
    const int tb = big ? 4096 : 0;

    hipLaunchKernelGGL(prep_all, dim3(tb + 80), dim3(256), 0, stream,
                       x, Wx, bx, Wy, by, W1, b1, W2, b2, wsb, wsf, xT, tb);
    if (big) {
        const int grid = 512;  // exactly 2 blocks/CU, 8 tiles/block, zero tail imbalance
        hipLaunchKernelGGL(nca_mfma_t, dim3(grid), dim3(256), 0, stream,
                           xT, wsb, wsf, out, grid);
    } else {
        const int grid = 1024;
        hipLaunchKernelGGL(nca_mfma_fb, dim3(grid), dim3(256), 0, stream,
                           x, wsb, wsf, out, grid);
    }
}